// Round 1
// baseline (487.589 us; speedup 1.0000x reference)
//
#include <hip/hip_runtime.h>

#define EPS 1e-5f
constexpr int HD = 128;   // node feature / hidden dim
constexpr int FCD = 64;   // fc hidden dim

typedef __attribute__((ext_vector_type(8))) short short8;
typedef __attribute__((ext_vector_type(4))) float floatx4;

// ---------- bf16 helpers ----------
__device__ inline ushort f2bf(float f){
  union{float f; unsigned u;} v; v.f = f;
  unsigned r = v.u + 0x7FFFu + ((v.u >> 16) & 1u);
  return (ushort)(r >> 16);
}
__device__ inline float bflo(unsigned u){ union{unsigned i; float f;} v; v.i = u << 16;        return v.f; }
__device__ inline float bfhi(unsigned u){ union{unsigned i; float f;} v; v.i = u & 0xFFFF0000u; return v.f; }
__device__ inline float bf2f(ushort u){ union{unsigned i; float f;} v; v.i = ((unsigned)u) << 16; return v.f; }

// ================= fused setup: edge histogram + batch rowptr + W pack ==========
// blocks [0,nEB):        LDS histogram of dst>>8, one global atomic per bucket
// blocks [nEB,nEB+nBB):  batchPtr[g] = first node of graph g (batch is sorted)
// blocks [nEB+nBB,+192): pack W1..W3 into fragment-major bf16 for MFMA B-operand
__global__ __launch_bounds__(256) void k_setup(const int* __restrict__ dst,
                                               int* __restrict__ bucketHist, int E, int nEB,
                                               const int* __restrict__ batch,
                                               int* __restrict__ batchPtr, int N, int G, int nBB,
                                               const float* __restrict__ W1,
                                               const float* __restrict__ W2,
                                               const float* __restrict__ W3,
                                               ushort* __restrict__ Wf){
  __shared__ int h[256];
  int t = threadIdx.x;
  int b = blockIdx.x;
  if (b < nEB){
    h[t] = 0;
    __syncthreads();
    int base = b*4096;
    #pragma unroll
    for (int k = 0; k < 16; ++k){
      int e = base + k*256 + t;
      if (e < E) atomicAdd(&h[dst[e] >> 8], 1);
    }
    __syncthreads();
    if (h[t]) atomicAdd(&bucketHist[t], h[t]);
  } else if (b < nEB + nBB){
    int i = (b - nEB)*256 + t;
    if (i < N){
      int bb = batch[i];
      int prev = (i == 0) ? -1 : batch[i-1];
      for (int g = prev + 1; g <= bb; ++g) batchPtr[g] = i;
      if (i == N-1)
        for (int g = bb + 1; g <= G; ++g) batchPtr[g] = N;
    }
  } else {
    int idx4 = b - nEB - nBB;            // 0..191
    int l = idx4 >> 6;
    int idx = (idx4 & 63)*256 + t;       // 0..16383
    const float* Ws = (l == 0) ? W1 : (l == 1) ? W2 : W3;
    int k = idx >> 7, n = idx & 127;
    float w = Ws[idx];
    int kb = k >> 5, q = (k >> 3) & 3, jj = k & 7;
    int nt = n >> 4, col = n & 15;
    Wf[(size_t)l*16384 + (((size_t)(kb*8 + nt)*64 + q*16 + col)*8 + jj)] = f2bf(w);
  }
}

// 1 block: exclusive scan of 256 bucket counts -> base & cursor
__global__ __launch_bounds__(256) void k_bscan(const int* __restrict__ bucketHist,
                                               int* __restrict__ bucketBase,
                                               int* __restrict__ bucketCursor){
  __shared__ int wt[4];
  int t = threadIdx.x, lane = t & 63, w = t >> 6;
  int v = bucketHist[t];
  int incl = v;
  #pragma unroll
  for (int o = 1; o < 64; o <<= 1){
    int x = __shfl_up(incl, o, 64);
    if (lane >= o) incl += x;
  }
  if (lane == 63) wt[w] = incl;
  __syncthreads();
  int woff = 0;
  for (int i = 0; i < w; ++i) woff += wt[i];
  int ex = woff + incl - v;
  bucketBase[t] = ex;
  bucketCursor[t] = ex;
}

// LDS-staged bucket scatter: stage 4096 edges grouped by bucket, reserve one
// global range per non-empty bucket, stream runs out contiguously.
__global__ __launch_bounds__(256) void k_bucket(const int* __restrict__ src,
                                                const int* __restrict__ dst,
                                                int* __restrict__ bucketCursor,
                                                int2* __restrict__ tmp, int E){
  __shared__ int h[256], ls[256], cur[256], gb[256];
  __shared__ int wt[4];
  __shared__ int2 staged[4096];
  __shared__ unsigned char bos[4096];
  int t = threadIdx.x, lane = t & 63, w = t >> 6;
  int base = blockIdx.x*4096;
  int2 ed[16]; int bk[16];
  h[t] = 0;
  __syncthreads();
  #pragma unroll
  for (int k = 0; k < 16; ++k){
    int e = base + k*256 + t;
    if (e < E){
      int s = src[e], d = dst[e];
      ed[k] = make_int2(s, d);
      bk[k] = d >> 8;
      atomicAdd(&h[bk[k]], 1);
    } else bk[k] = -1;
  }
  __syncthreads();
  // exclusive scan h -> ls
  int v = h[t];
  int incl = v;
  #pragma unroll
  for (int o = 1; o < 64; o <<= 1){
    int x = __shfl_up(incl, o, 64);
    if (lane >= o) incl += x;
  }
  if (lane == 63) wt[w] = incl;
  __syncthreads();
  int woff = 0;
  for (int i = 0; i < w; ++i) woff += wt[i];
  ls[t] = woff + incl - v;
  cur[t] = ls[t];
  if (v > 0) gb[t] = atomicAdd(&bucketCursor[t], v);
  __syncthreads();
  #pragma unroll
  for (int k = 0; k < 16; ++k){
    if (bk[k] >= 0){
      int lp = atomicAdd(&cur[bk[k]], 1);
      staged[lp] = ed[k];
      bos[lp] = (unsigned char)bk[k];
    }
  }
  __syncthreads();
  int nvalid = min(4096, E - base);
  #pragma unroll
  for (int k = 0; k < 16; ++k){
    int i = k*256 + t;
    if (i < nvalid){
      int b = bos[i];
      tmp[gb[b] + (i - ls[b])] = staged[i];
    }
  }
}

// one block per bucket: group by exact dst, emit rowptr/dis/csrc
__global__ __launch_bounds__(256) void k_csr(const int2* __restrict__ tmp,
                                             const int* __restrict__ bucketHist,
                                             const int* __restrict__ bucketBase,
                                             int* __restrict__ rowptr,
                                             float* __restrict__ dis,
                                             int* __restrict__ csrc, int N){
  __shared__ int h[256], ls[256], cur[256];
  __shared__ int wt[4];
  __shared__ int stagedSrc[6144];            // cap >> max bucket size (~4350)
  int b = blockIdx.x, t = threadIdx.x, lane = t & 63, w = t >> 6;
  int ebase = bucketBase[b];
  int cnt = bucketHist[b];
  int node0 = b << 8;
  h[t] = 0;
  __syncthreads();
  for (int i = t; i < cnt; i += 256){
    int2 e = tmp[ebase + i];
    atomicAdd(&h[e.y - node0], 1);
  }
  __syncthreads();
  int v = h[t];
  int incl = v;
  #pragma unroll
  for (int o = 1; o < 64; o <<= 1){
    int x = __shfl_up(incl, o, 64);
    if (lane >= o) incl += x;
  }
  if (lane == 63) wt[w] = incl;
  __syncthreads();
  int woff = 0;
  for (int i = 0; i < w; ++i) woff += wt[i];
  int ex = woff + incl - v;
  ls[t] = ex; cur[t] = ex;
  int d = node0 + t;
  if (d < N){
    rowptr[d+1] = ebase + ex + v;
    dis[d] = rsqrtf((float)v + 1.0f);
  }
  if (b == 0 && t == 0) rowptr[0] = 0;
  __syncthreads();
  for (int i = t; i < cnt; i += 256){
    int2 e = tmp[ebase + i];
    int lp = atomicAdd(&cur[e.y - node0], 1);
    stagedSrc[lp] = e.x;
  }
  __syncthreads();
  for (int i = t; i < cnt; i += 256)
    csrc[ebase + i] = stagedSrc[i];
}

// ------------------- GEMM: bf16 MFMA, fused BN-affine+ReLU on A, dis-scale on out ----
// MODE 0: A fp32 (= x), plain convert. MODE 1: A bf16 (= AGG), affine+relu in fp32.
template<int MODE>
__global__ __launch_bounds__(256) void k_gemm(const void* __restrict__ Av,
                                              const ushort* __restrict__ Wf,
                                              const float* __restrict__ sums,
                                              const float* __restrict__ g,
                                              const float* __restrict__ be,
                                              const float* __restrict__ dis,
                                              ushort* __restrict__ O, int n, float invN){
  __shared__ float aL[HD], bL[HD];
  int tid = threadIdx.x;
  if (MODE){
    if (tid < HD){
      float m = sums[tid]*invN;
      float var = fmaxf(sums[HD+tid]*invN - m*m, 0.f);
      float Ac = g[tid]*rsqrtf(var + EPS);
      aL[tid] = Ac; bL[tid] = be[tid] - m*Ac;
    }
    __syncthreads();
  }
  int lane = tid & 63, wave = tid >> 6;
  int quad = lane >> 4, r16 = lane & 15;
  int row = blockIdx.x*64 + wave*16 + r16;
  int rowc = min(row, n-1);
  floatx4 acc[8] = {};
  #pragma unroll
  for (int kb = 0; kb < 4; ++kb){
    int k0 = kb*32 + quad*8;
    short8 af;
    if (MODE){
      const ushort* Arow = (const ushort*)Av + (size_t)rowc*HD;
      short8 raw = *(const short8*)(Arow + k0);
      #pragma unroll
      for (int jj = 0; jj < 8; ++jj){
        float f = bf2f((ushort)raw[jj]);
        f = fmaxf(f*aL[k0+jj] + bL[k0+jj], 0.f);
        af[jj] = (short)f2bf(f);
      }
    } else {
      const float* Arow = (const float*)Av + (size_t)rowc*HD;
      float4 x0 = *(const float4*)(Arow + k0);
      float4 x1 = *(const float4*)(Arow + k0 + 4);
      af[0] = (short)f2bf(x0.x); af[1] = (short)f2bf(x0.y);
      af[2] = (short)f2bf(x0.z); af[3] = (short)f2bf(x0.w);
      af[4] = (short)f2bf(x1.x); af[5] = (short)f2bf(x1.y);
      af[6] = (short)f2bf(x1.z); af[7] = (short)f2bf(x1.w);
    }
    const ushort* wp = Wf + ((size_t)(kb*8)*64 + lane)*8;
    #pragma unroll
    for (int nt = 0; nt < 8; ++nt){
      short8 bf = *(const short8*)(wp + (size_t)nt*64*8);
      acc[nt] = __builtin_amdgcn_mfma_f32_16x16x32_bf16(af, bf, acc[nt], 0, 0, 0);
    }
  }
  int rbase = blockIdx.x*64 + wave*16 + quad*4;
  float ds[4];
  #pragma unroll
  for (int r = 0; r < 4; ++r) ds[r] = dis[min(rbase + r, n-1)];
  #pragma unroll
  for (int nt = 0; nt < 8; ++nt){
    #pragma unroll
    for (int r = 0; r < 4; ++r){
      int rr = rbase + r;
      if (rr < n) O[(size_t)rr*HD + nt*16 + r16] = f2bf(acc[nt][r]*ds[r]);
    }
  }
}

// ------------------- edge aggregation + fused BN-stats (direct atomics) -----------
__global__ __launch_bounds__(256) void k_gather(const ushort* __restrict__ hw,
                                                const int* __restrict__ rowptr,
                                                const int* __restrict__ csrc,
                                                const float* __restrict__ dis,
                                                ushort* __restrict__ agg,
                                                float* __restrict__ sumsOut, int N){
  __shared__ float2 sm[4][HD];
  int grp = threadIdx.x >> 4, j = threadIdx.x & 15;
  int wave = threadIdx.x >> 6, lane = threadIdx.x & 63;
  int i = blockIdx.x*16 + grp;
  bool valid = (i < N);
  int ic = valid ? i : N-1;
  uint4 q = ((const uint4*)(hw + (size_t)ic*HD))[j];
  float a[8];
  a[0] = bflo(q.x); a[1] = bfhi(q.x);
  a[2] = bflo(q.y); a[3] = bfhi(q.y);
  a[4] = bflo(q.z); a[5] = bfhi(q.z);
  a[6] = bflo(q.w); a[7] = bfhi(q.w);
  int e = rowptr[ic], e1 = rowptr[ic+1];
  #define ADD8(Q) \
    a[0] += bflo(Q.x); a[1] += bfhi(Q.x); \
    a[2] += bflo(Q.y); a[3] += bfhi(Q.y); \
    a[4] += bflo(Q.z); a[5] += bfhi(Q.z); \
    a[6] += bflo(Q.w); a[7] += bfhi(Q.w);
  while (e < e1 && (e & 3)){
    uint4 qq = ((const uint4*)(hw + (size_t)csrc[e]*HD))[j];
    ADD8(qq);
    e++;
  }
  int4 c0, c1;
  if (e + 8 <= e1){
    c0 = *(const int4*)&csrc[e];
    c1 = *(const int4*)&csrc[e+4];
  }
  while (e + 8 <= e1){
    int en = e + 8;
    int4 n0, n1;
    if (en + 8 <= e1){
      n0 = *(const int4*)&csrc[en];
      n1 = *(const int4*)&csrc[en+4];
    }
    uint4 q0 = ((const uint4*)(hw + (size_t)c0.x*HD))[j];
    uint4 q1 = ((const uint4*)(hw + (size_t)c0.y*HD))[j];
    uint4 q2 = ((const uint4*)(hw + (size_t)c0.z*HD))[j];
    uint4 q3 = ((const uint4*)(hw + (size_t)c0.w*HD))[j];
    uint4 q4 = ((const uint4*)(hw + (size_t)c1.x*HD))[j];
    uint4 q5 = ((const uint4*)(hw + (size_t)c1.y*HD))[j];
    uint4 q6 = ((const uint4*)(hw + (size_t)c1.z*HD))[j];
    uint4 q7 = ((const uint4*)(hw + (size_t)c1.w*HD))[j];
    ADD8(q0); ADD8(q1); ADD8(q2); ADD8(q3);
    ADD8(q4); ADD8(q5); ADD8(q6); ADD8(q7);
    c0 = n0; c1 = n1; e = en;
  }
  if (e + 4 <= e1){
    int4 tt = *(const int4*)&csrc[e];
    uint4 q0 = ((const uint4*)(hw + (size_t)tt.x*HD))[j];
    uint4 q1 = ((const uint4*)(hw + (size_t)tt.y*HD))[j];
    uint4 q2 = ((const uint4*)(hw + (size_t)tt.z*HD))[j];
    uint4 q3 = ((const uint4*)(hw + (size_t)tt.w*HD))[j];
    ADD8(q0); ADD8(q1); ADD8(q2); ADD8(q3);
    e += 4;
  }
  for (; e < e1; ++e){
    uint4 qq = ((const uint4*)(hw + (size_t)csrc[e]*HD))[j];
    ADD8(qq);
  }
  #undef ADD8
  float sc = dis[ic];
  #pragma unroll
  for (int k = 0; k < 8; ++k) a[k] *= sc;
  if (valid){
    uint4 o;
    o.x = (unsigned)f2bf(a[0]) | ((unsigned)f2bf(a[1]) << 16);
    o.y = (unsigned)f2bf(a[2]) | ((unsigned)f2bf(a[3]) << 16);
    o.z = (unsigned)f2bf(a[4]) | ((unsigned)f2bf(a[5]) << 16);
    o.w = (unsigned)f2bf(a[6]) | ((unsigned)f2bf(a[7]) << 16);
    ((uint4*)(agg + (size_t)i*HD))[j] = o;
  }
  float z = valid ? 1.f : 0.f;
  #pragma unroll
  for (int k = 0; k < 8; ++k){
    float s = a[k]*z, qq = a[k]*a[k]*z;
    s  += __shfl_xor(s, 16);  s  += __shfl_xor(s, 32);
    qq += __shfl_xor(qq, 16); qq += __shfl_xor(qq, 32);
    if (lane < 16) sm[wave][lane*8 + k] = make_float2(s, qq);
  }
  __syncthreads();
  int t = threadIdx.x;
  if (t < HD){
    float2 r0 = sm[0][t], r1 = sm[1][t], r2 = sm[2][t], r3 = sm[3][t];
    atomicAdd(&sumsOut[t],      r0.x + r1.x + r2.x + r3.x);
    atomicAdd(&sumsOut[HD + t], r0.y + r1.y + r2.y + r3.y);
  }
}

// ------------------- mean pool: one block per graph (fused BN3+ReLU) --------------
__global__ __launch_bounds__(256) void k_pool(const ushort* __restrict__ h,
                                              const int* __restrict__ batchPtr,
                                              const float* __restrict__ sums,
                                              const float* __restrict__ gw,
                                              const float* __restrict__ be,
                                              float* __restrict__ pooled, float invN){
  __shared__ float sm[4][HD];
  int g = blockIdx.x;
  int start = batchPtr[g], end = batchPtr[g+1];
  int tid = threadIdx.x;
  int j = tid & 15, r = tid >> 4;
  int wave = tid >> 6, lane = tid & 63;
  float aC[8], bC[8];
  #pragma unroll
  for (int k = 0; k < 8; ++k){
    int c = j*8 + k;
    float m = sums[c]*invN;
    float var = fmaxf(sums[HD+c]*invN - m*m, 0.f);
    float A = gw[c]*rsqrtf(var + EPS);
    aC[k] = A; bC[k] = be[c] - m*A;
  }
  float acc[8] = {};
  for (int i = start + r; i < end; i += 16){
    uint4 q = ((const uint4*)(h + (size_t)i*HD))[j];
    acc[0] += fmaxf(bflo(q.x)*aC[0] + bC[0], 0.f);
    acc[1] += fmaxf(bfhi(q.x)*aC[1] + bC[1], 0.f);
    acc[2] += fmaxf(bflo(q.y)*aC[2] + bC[2], 0.f);
    acc[3] += fmaxf(bfhi(q.y)*aC[3] + bC[3], 0.f);
    acc[4] += fmaxf(bflo(q.z)*aC[4] + bC[4], 0.f);
    acc[5] += fmaxf(bfhi(q.z)*aC[5] + bC[5], 0.f);
    acc[6] += fmaxf(bflo(q.w)*aC[6] + bC[6], 0.f);
    acc[7] += fmaxf(bfhi(q.w)*aC[7] + bC[7], 0.f);
  }
  // reduce the 16 row-lanes: bits 4,5 of lane via shuffle, waves via LDS
  #pragma unroll
  for (int k = 0; k < 8; ++k){
    float s = acc[k];
    s += __shfl_xor(s, 16); s += __shfl_xor(s, 32);
    if (lane < 16) sm[wave][lane*8 + k] = s;
  }
  __syncthreads();
  if (tid < HD){
    float tot = sm[0][tid] + sm[1][tid] + sm[2][tid] + sm[3][tid];
    float inv = 1.0f / (float)max(end - start, 1);
    pooled[(size_t)g*HD + tid] = tot * inv;
  }
}

// ------------------- FC head (stats fused into fc1) -------------------

__global__ __launch_bounds__(64) void k_fc1(const float* __restrict__ pooled,
                                            const float* __restrict__ W,
                                            const float* __restrict__ b,
                                            float* __restrict__ z,
                                            float* __restrict__ sums2, int G){
  int g = blockIdx.x, j = threadIdx.x;
  const float* pr = pooled + (size_t)g*HD;
  float acc = 0.f;
  #pragma unroll 8
  for (int k = 0; k < HD; ++k)
    acc += pr[k] * W[k*FCD + j];
  float zv = acc + b[j];
  z[(size_t)g*FCD + j] = zv;
  atomicAdd(&sums2[j], zv);
  atomicAdd(&sums2[FCD + j], zv*zv);
}

__global__ __launch_bounds__(64) void k_final(const float* __restrict__ z,
                                              const float* __restrict__ sums2,
                                              const float* __restrict__ g,
                                              const float* __restrict__ be,
                                              const float* __restrict__ w2,
                                              const float* __restrict__ b2,
                                              float* __restrict__ out, int G, float invG){
  int gg = blockIdx.x, c = threadIdx.x;
  float m = sums2[c]*invG;
  float var = fmaxf(sums2[FCD+c]*invG - m*m, 0.f);
  float A = g[c]*rsqrtf(var + EPS);
  float B = be[c] - m*A;
  float v = fmaxf(z[(size_t)gg*FCD + c]*A + B, 0.f) * w2[c];
  #pragma unroll
  for (int o = 32; o > 0; o >>= 1) v += __shfl_down(v, o, 64);
  if (c == 0) out[gg] = v + b2[0];
}

// ------------------- launch -------------------

extern "C" void kernel_launch(void* const* d_in, const int* in_sizes, int n_in,
                              void* d_out, int out_size, void* d_ws, size_t ws_size,
                              hipStream_t stream){
  const float* x    = (const float*)d_in[0];
  const int*   ei   = (const int*)d_in[1];
  const int*   batch= (const int*)d_in[2];
  const float* W1 = (const float*)d_in[3];
  const float* g1 = (const float*)d_in[5];
  const float* be1= (const float*)d_in[6];
  const float* W2 = (const float*)d_in[7];
  const float* g2 = (const float*)d_in[9];
  const float* be2= (const float*)d_in[10];
  const float* W3 = (const float*)d_in[11];
  const float* g3 = (const float*)d_in[13];
  const float* be3= (const float*)d_in[14];
  const float* fcW1 = (const float*)d_in[15];
  const float* fcb1 = (const float*)d_in[16];
  const float* fcg1 = (const float*)d_in[17];
  const float* fcbe1= (const float*)d_in[18];
  const float* fcW2 = (const float*)d_in[19];
  const float* fcb2 = (const float*)d_in[20];
  float* out = (float*)d_out;

  const int N = in_sizes[0] / HD;      // 50000
  const int E = in_sizes[1] / 2;       // 800000
  const int G = out_size;              // 500

  const int* esrc = ei;
  const int* edst = ei + E;

  char* p = (char*)d_ws;
  auto alloc = [&](size_t bytes)->void*{
    void* r = (void*)p; p += (bytes + 255) & ~(size_t)255; return r;
  };
  int gatherBlocks = (N + 15)/16;
  int nEB = (E + 4095)/4096;           // 196 edge blocks
  int nBB = (N + 255)/256;             // 196 batch-ptr blocks
  int NB  = (N + 255)/256;             // 196 node buckets (<=256 required)

  // zeroed region: bucketHist | sumsL[3][2*HD] | sums2[2*FCD]
  size_t zeroBytes = 256*4 + 3*2*HD*4 + 2*FCD*4;   // 4608 B
  int*    bucketHist  = (int*) alloc(zeroBytes);
  float*  sumsL  = (float*)(bucketHist + 256);
  float*  sums2  = sumsL + 3*2*HD;
  int*    bucketBase  = (int*) alloc(256*4);
  int*    bucketCursor= (int*) alloc(256*4);
  int*    batchPtr = (int*) alloc((size_t)(G+1)*4);
  int2*   tmp    = (int2*)  alloc((size_t)E*8);
  int*    rowptr = (int*)   alloc((size_t)(N+1)*4);
  int*    csrc   = (int*)   alloc((size_t)E*4);
  float*  dis    = (float*) alloc((size_t)N*4);
  ushort* HWb    = (ushort*)alloc((size_t)N*HD*2);
  ushort* AGG    = (ushort*)alloc((size_t)N*HD*2);
  ushort* Wf     = (ushort*)alloc((size_t)3*HD*HD*2);
  float*  pooled = (float*) alloc((size_t)G*HD*4);
  float*  zbuf   = (float*) alloc((size_t)G*FCD*4);

  float invN = 1.0f/(float)N, invG = 1.0f/(float)G;

  hipMemsetAsync(bucketHist, 0, zeroBytes, stream);
  k_setup <<<nEB + nBB + 3*(HD*HD/256), 256, 0, stream>>>(
      edst, bucketHist, E, nEB, batch, batchPtr, N, G, nBB, W1, W2, W3, Wf);
  k_bscan <<<1, 256, 0, stream>>>(bucketHist, bucketBase, bucketCursor);
  k_bucket<<<nEB, 256, 0, stream>>>(esrc, edst, bucketCursor, tmp, E);
  k_csr   <<<NB, 256, 0, stream>>>(tmp, bucketHist, bucketBase, rowptr, dis, csrc, N);

  int gemmBlocks = (N + 63)/64;

  // layer 1
  k_gemm<0> <<<gemmBlocks, 256, 0, stream>>>(x,   Wf,         nullptr, nullptr, nullptr, dis, HWb, N, invN);
  k_gather  <<<gatherBlocks, 256, 0, stream>>>(HWb, rowptr, csrc, dis, AGG, sumsL, N);
  // layer 2 (BN1+ReLU fused into A-load)
  k_gemm<1> <<<gemmBlocks, 256, 0, stream>>>(AGG, Wf + 16384, sumsL, g1, be1, dis, HWb, N, invN);
  k_gather  <<<gatherBlocks, 256, 0, stream>>>(HWb, rowptr, csrc, dis, AGG, sumsL + 2*HD, N);
  // layer 3 (BN2+ReLU fused into A-load)
  k_gemm<1> <<<gemmBlocks, 256, 0, stream>>>(AGG, Wf + 32768, sumsL + 2*HD, g2, be2, dis, HWb, N, invN);
  k_gather  <<<gatherBlocks, 256, 0, stream>>>(HWb, rowptr, csrc, dis, AGG, sumsL + 4*HD, N);

  // pool (BN3+ReLU fused, direct per-graph write) + head
  k_pool  <<<G, 256, 0, stream>>>(AGG, batchPtr, sumsL + 4*HD, g3, be3, pooled, invN);
  k_fc1   <<<G, FCD, 0, stream>>>(pooled, fcW1, fcb1, zbuf, sums2, G);
  k_final <<<G, FCD, 0, stream>>>(zbuf, sums2, fcg1, fcbe1, fcW2, fcb2, out, G, invG);
}